// Round 13
// baseline (283.913 us; speedup 1.0000x reference)
//
#include <hip/hip_runtime.h>

// Problem constants (batch: (3, 1280, 1280) fp32, PATCH=16)
#define PS 16
#define HW 1280
#define NPS 80            // patches per side
#define NP (NPS * NPS)    // 6400 patches
#define GS 12             // floats per record: 9 gram + 1 sq + 2 pad (48B)

#define NBLK 1280         // 5 blocks/CU; capacity at VGPR<=64 is 6/CU -> slack
// phase 2 tiling: 80 rows x 256 cols per tile
#define MI 80
#define MJ 256
#define NT2 ((NP / MI) * (NP / MJ))   // 80*25 = 2000
// phase 3 tiling: 16 rows x 1280 cols per tile (r12 write geometry)
#define WI 16
#define NT3 ((NP / WI) * 5)           // 400*5 = 2000

typedef float vf4 __attribute__((ext_vector_type(4)));

__device__ __forceinline__ unsigned f2ord(float f) {
    unsigned u = __float_as_uint(f);
    return (u & 0x80000000u) ? ~u : (u | 0x80000000u);
}
__device__ __forceinline__ float ord2f(unsigned m) {
    return (m & 0x80000000u) ? __uint_as_float(m & 0x7FFFFFFFu) : __uint_as_float(~m);
}

// Ticket grid-barrier: no reset needed across calls (monotone counter);
// bar is zeroed per launch by an async memset anyway. Release: threadfence
// (L2 writeback) before arrive; acquire fence after spin exit.
__device__ __forceinline__ void grid_bar(unsigned* bar, int t) {
    __syncthreads();
    if (t == 0) {
        __threadfence();
        const unsigned old = __hip_atomic_fetch_add(bar, 1u, __ATOMIC_ACQ_REL,
                                                    __HIP_MEMORY_SCOPE_AGENT);
        const unsigned target = (old / NBLK + 1u) * NBLK;
        while (__hip_atomic_load(bar, __ATOMIC_RELAXED,
                                 __HIP_MEMORY_SCOPE_AGENT) < target)
            __builtin_amdgcn_s_sleep(4);
        __builtin_amdgcn_fence(__ATOMIC_ACQUIRE, "agent");
    }
    __syncthreads();
}

__global__ __launch_bounds__(320, 8) void fused(const float* __restrict__ x,
                                                float* __restrict__ G,
                                                unsigned* __restrict__ mm,
                                                unsigned* __restrict__ bar,
                                                float* __restrict__ out) {
    const int t = threadIdx.x;
    const int w = t >> 6, l = t & 63;
    __shared__ float shi[MI * 8];   // 2.5KB: i-tiles (phase2: 80 rows, phase3: 16)
    __shared__ float smax[5];
    __shared__ float sinv;

    // ---- phase 1: gram — wave per patch; grid covers NP exactly (1280*5) ----
    {
        const int n = blockIdx.x * 5 + w;   // < 6400 always
        const int pi = n / NPS, pj = n % NPS;
        const int r = l >> 2, c = (l & 3) * 4;
        const size_t base = (size_t)(pi * PS + r) * HW + pj * PS + c;
        const float4 A = *(const float4*)(x + base);
        const float4 B = *(const float4*)(x + base + (size_t)HW * HW);
        const float4 C = *(const float4*)(x + base + 2 * (size_t)HW * HW);
        float p[6];
        p[0] = A.x * A.x + A.y * A.y + A.z * A.z + A.w * A.w;
        p[1] = A.x * B.x + A.y * B.y + A.z * B.z + A.w * B.w;
        p[2] = A.x * C.x + A.y * C.y + A.z * C.z + A.w * C.w;
        p[3] = B.x * B.x + B.y * B.y + B.z * B.z + B.w * B.w;
        p[4] = B.x * C.x + B.y * C.y + B.z * C.z + B.w * C.w;
        p[5] = C.x * C.x + C.y * C.y + C.z * C.z + C.w * C.w;
#pragma unroll
        for (int k = 0; k < 6; ++k) {
            float v = p[k];
#pragma unroll
            for (int off = 32; off; off >>= 1) v += __shfl_xor(v, off);
            p[k] = v;
        }
        if (l == 0) {
            const float sc = 1.0f / 768.0f;
            const float g0 = p[0] * sc, g1 = p[1] * sc, g2 = p[2] * sc;
            const float g3 = p[3] * sc, g4 = p[4] * sc, g5 = p[5] * sc;
            const float row[9] = {g0, g1, g2, g1, g3, g4, g2, g4, g5};
            float s = 0.f;
#pragma unroll
            for (int k = 0; k < 9; ++k) s = fmaf(row[k], row[k], s);
            float* dst = G + (size_t)n * GS;
            *(float4*)(dst)     = make_float4(row[0], row[1], row[2], row[3]);
            *(float4*)(dst + 4) = make_float4(row[4], row[5], row[6], row[7]);
            *(float4*)(dst + 8) = make_float4(row[8], s, 0.f, 0.f);
        }
    }

    grid_bar(bar, t);   // G visible device-wide

    // ---- phase 2: max over upper-band tiles (symmetric, diag == 0) ----
    float vmax = -3.4e38f;
    for (int tau = blockIdx.x; tau < NT2; tau += NBLK) {
        const int bi = tau / (NP / MJ), bj = tau % (NP / MJ);
        const int i0 = bi * MI, j0 = bj * MJ;
        if (i0 > j0 + MJ - 1) continue;   // block-uniform skip
        __syncthreads();
        if (t < MI) {
            const float* src = G + (size_t)(i0 + t) * GS;
            const float4 a = *(const float4*)(src);
            const float4 b = *(const float4*)(src + 4);
            const float4 q = *(const float4*)(src + 8);
            float* d = shi + t * 8;
            d[0] = -2.f * a.x; d[1] = -4.f * a.y; d[2] = -4.f * a.z;
            d[3] = -2.f * b.x; d[4] = -4.f * b.y; d[5] = -2.f * q.x;
            d[6] = q.y; d[7] = 0.f;
        }
        __syncthreads();
        const int j = j0 + l * 4;
        float gj[4][6], sj[4];
#pragma unroll
        for (int c = 0; c < 4; ++c) {
            const float* src = G + (size_t)(j + c) * GS;
            const float4 a = *(const float4*)(src);
            const float4 b = *(const float4*)(src + 4);
            const float4 q = *(const float4*)(src + 8);
            gj[c][0] = a.x; gj[c][1] = a.y; gj[c][2] = a.z;
            gj[c][3] = b.x; gj[c][4] = b.y; gj[c][5] = q.x;
            sj[c] = q.y;
        }
#pragma unroll 4
        for (int rr = 0; rr < MI / 5; ++rr) {   // 16 rows per wave
            const int r = w * (MI / 5) + rr;
            const float4 A = *(const float4*)(shi + r * 8);
            const float4 B = *(const float4*)(shi + r * 8 + 4);
            const float si = B.z;
#pragma unroll
            for (int c = 0; c < 4; ++c) {
                float acc = si + sj[c];
                acc = fmaf(A.x, gj[c][0], acc);
                acc = fmaf(A.y, gj[c][1], acc);
                acc = fmaf(A.z, gj[c][2], acc);
                acc = fmaf(A.w, gj[c][3], acc);
                acc = fmaf(B.x, gj[c][4], acc);
                acc = fmaf(B.y, gj[c][5], acc);
                vmax = fmaxf(vmax, acc);
            }
        }
    }
#pragma unroll
    for (int off = 32; off; off >>= 1) vmax = fmaxf(vmax, __shfl_xor(vmax, off));
    if (l == 0) smax[w] = vmax;
    __syncthreads();
    if (t == 0) {
        float bm = fmaxf(fmaxf(fmaxf(smax[0], smax[1]), fmaxf(smax[2], smax[3])), smax[4]);
        atomicMax(mm, f2ord(bm));
    }

    grid_bar(bar, t);   // all maxes merged

    if (t == 0) sinv = 1.0f / ord2f(atomicOr(mm, 0u));
    __syncthreads();
    const float inv = sinv;

    // ---- phase 3: normalized write (r12 geometry: 16x1280 slabs, vf4) ----
    for (int tau = blockIdx.x; tau < NT3; tau += NBLK) {
        const int bi = tau / 5, bjc = tau % 5;    // bjc fastest: linear slabs
        const int i0 = bi * WI;
        const int jw = bjc * 1280 + w * 256 + l * 4;
        __syncthreads();
        if (t < WI) {
            const float* src = G + (size_t)(i0 + t) * GS;
            const float4 a = *(const float4*)(src);
            const float4 b = *(const float4*)(src + 4);
            const float4 q = *(const float4*)(src + 8);
            const float m2 = -2.f * inv, m4 = -4.f * inv;
            float* d = shi + t * 8;
            d[0] = m2 * a.x; d[1] = m4 * a.y; d[2] = m4 * a.z;
            d[3] = m2 * b.x; d[4] = m4 * b.y; d[5] = m2 * q.x;
            d[6] = inv * q.y; d[7] = 0.f;
        }
        float gj[4][6], bj[4];
#pragma unroll
        for (int c = 0; c < 4; ++c) {
            const float* src = G + (size_t)(jw + c) * GS;
            const float4 a = *(const float4*)(src);
            const float4 b = *(const float4*)(src + 4);
            const float4 q = *(const float4*)(src + 8);
            gj[c][0] = a.x; gj[c][1] = a.y; gj[c][2] = a.z;
            gj[c][3] = b.x; gj[c][4] = b.y; gj[c][5] = q.x;
            bj[c] = inv * q.y;
        }
        __syncthreads();
        float* dst = out + (size_t)i0 * NP + jw;
#pragma unroll 4
        for (int rr = 0; rr < WI; ++rr) {
            const float4 A = *(const float4*)(shi + rr * 8);
            const float4 B = *(const float4*)(shi + rr * 8 + 4);
            const float hi = B.z;
            vf4 dv;
#pragma unroll
            for (int c = 0; c < 4; ++c) {
                float acc = hi + bj[c];
                acc = fmaf(A.x, gj[c][0], acc);
                acc = fmaf(A.y, gj[c][1], acc);
                acc = fmaf(A.z, gj[c][2], acc);
                acc = fmaf(A.w, gj[c][3], acc);
                acc = fmaf(B.x, gj[c][4], acc);
                acc = fmaf(B.y, gj[c][5], acc);
                dv[c] = acc;
            }
            *(vf4*)dst = dv;
            dst += NP;
        }
    }
}

extern "C" void kernel_launch(void* const* d_in, const int* in_sizes, int n_in,
                              void* d_out, int out_size, void* d_ws, size_t ws_size,
                              hipStream_t stream) {
    (void)in_sizes; (void)n_in; (void)out_size; (void)ws_size;
    const float* x = (const float*)d_in[0];
    float* out = (float*)d_out;
    char* ws = (char*)d_ws;
    float* G = (float*)ws;                       // 307200 B
    unsigned* mm = (unsigned*)(ws + 307200);
    unsigned* bar = mm + 1;

    hipMemsetAsync(mm, 0, 8, stream);            // mm=0 (max identity), bar=0
    fused<<<NBLK, 320, 0, stream>>>(x, G, mm, bar, out);
}

// Round 14
// 150.259 us; speedup vs baseline: 1.8895x; 1.8895x over previous
//
#include <hip/hip_runtime.h>

// Problem constants (batch: (3, 1280, 1280) fp32, PATCH=16)
#define PS 16
#define HW 1280
#define NPS 80            // patches per side
#define NP (NPS * NPS)    // 6400 patches
#define GS 12             // floats per record: 9 gram + 1 sq + 2 pad (48B)

#define FB 768            // grid: 3 blocks/CU — guaranteed co-resident by
                          // __launch_bounds__(320,4) (16 waves/CU >= 3x5)
// phase 2 tiling: 80 rows x 256 cols
#define MI 80
#define MJ 256
#define NT2 ((NP / MI) * (NP / MJ))   // 2000
// phase 3 tiling: 16 rows x 1280 cols (r12 write geometry)
#define WI 16
#define NT3 ((NP / WI) * 5)           // 2000

typedef float vf4 __attribute__((ext_vector_type(4)));

__device__ __forceinline__ unsigned f2ord(float f) {
    unsigned u = __float_as_uint(f);
    return (u & 0x80000000u) ? ~u : (u | 0x80000000u);
}
__device__ __forceinline__ float ord2f(unsigned m) {
    return (m & 0x80000000u) ? __uint_as_float(m & 0x7FFFFFFFu) : __uint_as_float(~m);
}

// Ticket grid-barrier (validated correct in r13). Release via ACQ_REL RMW;
// RELAXED spin polls (no per-poll cache invalidate!) + one acquire at exit.
__device__ __forceinline__ void grid_bar(unsigned* bar, int t) {
    __syncthreads();
    if (t == 0) {
        __threadfence();
        const unsigned old = __hip_atomic_fetch_add(bar, 1u, __ATOMIC_ACQ_REL,
                                                    __HIP_MEMORY_SCOPE_AGENT);
        const unsigned target = (old / FB + 1u) * FB;
        while (__hip_atomic_load(bar, __ATOMIC_RELAXED,
                                 __HIP_MEMORY_SCOPE_AGENT) < target)
            __builtin_amdgcn_s_sleep(8);
        __builtin_amdgcn_fence(__ATOMIC_ACQUIRE, "agent");
    }
    __syncthreads();
}

__global__ __launch_bounds__(320, 4) void fused(const float* __restrict__ x,
                                                float* __restrict__ G,
                                                unsigned* __restrict__ mm,
                                                unsigned* __restrict__ bar,
                                                float* __restrict__ out) {
    const int t = threadIdx.x;
    const int w = t >> 6, l = t & 63;
    __shared__ float shi[MI * 8];   // 2.5KB i-tile
    __shared__ float smax[5];
    __shared__ float sinv;

    // ---- phase 1: gram — wave per patch, grid-stride (3840 waves) ----
    for (int n = blockIdx.x * 5 + w; n < NP; n += FB * 5) {
        const int pi = n / NPS, pj = n % NPS;
        const int r = l >> 2, c = (l & 3) * 4;
        const size_t base = (size_t)(pi * PS + r) * HW + pj * PS + c;
        const float4 A = *(const float4*)(x + base);
        const float4 B = *(const float4*)(x + base + (size_t)HW * HW);
        const float4 C = *(const float4*)(x + base + 2 * (size_t)HW * HW);
        float p[6];
        p[0] = A.x * A.x + A.y * A.y + A.z * A.z + A.w * A.w;
        p[1] = A.x * B.x + A.y * B.y + A.z * B.z + A.w * B.w;
        p[2] = A.x * C.x + A.y * C.y + A.z * C.z + A.w * C.w;
        p[3] = B.x * B.x + B.y * B.y + B.z * B.z + B.w * B.w;
        p[4] = B.x * C.x + B.y * C.y + B.z * C.z + B.w * C.w;
        p[5] = C.x * C.x + C.y * C.y + C.z * C.z + C.w * C.w;
#pragma unroll
        for (int k = 0; k < 6; ++k) {
            float v = p[k];
#pragma unroll
            for (int off = 32; off; off >>= 1) v += __shfl_xor(v, off);
            p[k] = v;
        }
        if (l == 0) {
            const float sc = 1.0f / 768.0f;
            const float g0 = p[0] * sc, g1 = p[1] * sc, g2 = p[2] * sc;
            const float g3 = p[3] * sc, g4 = p[4] * sc, g5 = p[5] * sc;
            const float row[9] = {g0, g1, g2, g1, g3, g4, g2, g4, g5};
            float s = 0.f;
#pragma unroll
            for (int k = 0; k < 9; ++k) s = fmaf(row[k], row[k], s);
            float* dst = G + (size_t)n * GS;
            *(float4*)(dst)     = make_float4(row[0], row[1], row[2], row[3]);
            *(float4*)(dst + 4) = make_float4(row[4], row[5], row[6], row[7]);
            *(float4*)(dst + 8) = make_float4(row[8], s, 0.f, 0.f);
        }
    }

    grid_bar(bar, t);   // G visible device-wide

    // ---- phase 2: max over upper-band tiles (symmetric, diag == 0) ----
    float vmax = -3.4e38f;
    for (int tau = blockIdx.x; tau < NT2; tau += FB) {
        const int bi = tau / (NP / MJ), bj = tau % (NP / MJ);
        const int i0 = bi * MI, j0 = bj * MJ;
        if (i0 > j0 + MJ - 1) continue;   // block-uniform skip
        __syncthreads();
        if (t < MI) {
            const float* src = G + (size_t)(i0 + t) * GS;
            const float4 a = *(const float4*)(src);
            const float4 b = *(const float4*)(src + 4);
            const float4 q = *(const float4*)(src + 8);
            float* d = shi + t * 8;
            d[0] = -2.f * a.x; d[1] = -4.f * a.y; d[2] = -4.f * a.z;
            d[3] = -2.f * b.x; d[4] = -4.f * b.y; d[5] = -2.f * q.x;
            d[6] = q.y; d[7] = 0.f;
        }
        __syncthreads();
        const int j = j0 + l * 4;
        float gj[4][6], sj[4];
#pragma unroll
        for (int c = 0; c < 4; ++c) {
            const float* src = G + (size_t)(j + c) * GS;
            const float4 a = *(const float4*)(src);
            const float4 b = *(const float4*)(src + 4);
            const float4 q = *(const float4*)(src + 8);
            gj[c][0] = a.x; gj[c][1] = a.y; gj[c][2] = a.z;
            gj[c][3] = b.x; gj[c][4] = b.y; gj[c][5] = q.x;
            sj[c] = q.y;
        }
#pragma unroll 4
        for (int rr = 0; rr < MI / 5; ++rr) {   // 16 rows per wave
            const int r = w * (MI / 5) + rr;
            const float4 A = *(const float4*)(shi + r * 8);
            const float4 B = *(const float4*)(shi + r * 8 + 4);
            const float si = B.z;
#pragma unroll
            for (int c = 0; c < 4; ++c) {
                float acc = si + sj[c];
                acc = fmaf(A.x, gj[c][0], acc);
                acc = fmaf(A.y, gj[c][1], acc);
                acc = fmaf(A.z, gj[c][2], acc);
                acc = fmaf(A.w, gj[c][3], acc);
                acc = fmaf(B.x, gj[c][4], acc);
                acc = fmaf(B.y, gj[c][5], acc);
                vmax = fmaxf(vmax, acc);
            }
        }
    }
#pragma unroll
    for (int off = 32; off; off >>= 1) vmax = fmaxf(vmax, __shfl_xor(vmax, off));
    if (l == 0) smax[w] = vmax;
    __syncthreads();
    if (t == 0) {
        float bm = fmaxf(fmaxf(fmaxf(smax[0], smax[1]), fmaxf(smax[2], smax[3])), smax[4]);
        atomicMax(mm, f2ord(bm));
    }

    grid_bar(bar, t);   // all maxes merged

    if (t == 0) sinv = 1.0f / ord2f(atomicOr(mm, 0u));
    __syncthreads();
    const float inv = sinv;

    // ---- phase 3: normalized write (16x1280 slabs, vf4, j-fastest) ----
    for (int tau = blockIdx.x; tau < NT3; tau += FB) {
        const int bi = tau / 5, bjc = tau % 5;
        const int i0 = bi * WI;
        const int jw = bjc * 1280 + w * 256 + l * 4;
        __syncthreads();
        if (t < WI) {
            const float* src = G + (size_t)(i0 + t) * GS;
            const float4 a = *(const float4*)(src);
            const float4 b = *(const float4*)(src + 4);
            const float4 q = *(const float4*)(src + 8);
            const float m2 = -2.f * inv, m4 = -4.f * inv;
            float* d = shi + t * 8;
            d[0] = m2 * a.x; d[1] = m4 * a.y; d[2] = m4 * a.z;
            d[3] = m2 * b.x; d[4] = m4 * b.y; d[5] = m2 * q.x;
            d[6] = inv * q.y; d[7] = 0.f;
        }
        float gj[4][6], bj[4];
#pragma unroll
        for (int c = 0; c < 4; ++c) {
            const float* src = G + (size_t)(jw + c) * GS;
            const float4 a = *(const float4*)(src);
            const float4 b = *(const float4*)(src + 4);
            const float4 q = *(const float4*)(src + 8);
            gj[c][0] = a.x; gj[c][1] = a.y; gj[c][2] = a.z;
            gj[c][3] = b.x; gj[c][4] = b.y; gj[c][5] = q.x;
            bj[c] = inv * q.y;
        }
        __syncthreads();
        float* dst = out + (size_t)i0 * NP + jw;
#pragma unroll 4
        for (int rr = 0; rr < WI; ++rr) {
            const float4 A = *(const float4*)(shi + rr * 8);
            const float4 B = *(const float4*)(shi + rr * 8 + 4);
            const float hi = B.z;
            vf4 dv;
#pragma unroll
            for (int c = 0; c < 4; ++c) {
                float acc = hi + bj[c];
                acc = fmaf(A.x, gj[c][0], acc);
                acc = fmaf(A.y, gj[c][1], acc);
                acc = fmaf(A.z, gj[c][2], acc);
                acc = fmaf(A.w, gj[c][3], acc);
                acc = fmaf(B.x, gj[c][4], acc);
                acc = fmaf(B.y, gj[c][5], acc);
                dv[c] = acc;
            }
            *(vf4*)dst = dv;
            dst += NP;
        }
    }
}

extern "C" void kernel_launch(void* const* d_in, const int* in_sizes, int n_in,
                              void* d_out, int out_size, void* d_ws, size_t ws_size,
                              hipStream_t stream) {
    (void)in_sizes; (void)n_in; (void)out_size; (void)ws_size;
    const float* x = (const float*)d_in[0];
    float* out = (float*)d_out;
    char* ws = (char*)d_ws;
    float* G = (float*)ws;                       // 307200 B
    unsigned* mm = (unsigned*)(ws + 307200);
    unsigned* bar = mm + 1;

    hipMemsetAsync(mm, 0, 8, stream);            // mm=0 (max identity), bar=0
    fused<<<FB, 320, 0, stream>>>(x, G, mm, bar, out);
}

// Round 16
// 110.605 us; speedup vs baseline: 2.5669x; 1.3585x over previous
//
#include <hip/hip_runtime.h>

// Problem constants (batch: (3, 1280, 1280) fp32, PATCH=16)
#define PS 16
#define HW 1280
#define NPS 80            // patches per side
#define NP (NPS * NPS)    // 6400 patches
#define GS 12             // floats per record: 9 gram + 1 sq + 2 pad (48B)

#define FB 768            // fused grid: 3 blocks/CU dispatched; capacity at
                          // VGPR<=64 (256-thr blocks) is ~8/CU -> 2.7x slack
// phase 2 tiling: 64 rows x 256 cols (r7/r12 geometry)
#define MI 64
#define MJ 256
#define NT2 ((NP / MI) * (NP / MJ))   // 100*25 = 2500
// write tiling: 16 rows x 1280 cols (r12 geometry)
#define WI 16

typedef float vf4 __attribute__((ext_vector_type(4)));

__device__ __forceinline__ unsigned f2ord(float f) {
    unsigned u = __float_as_uint(f);
    return (u & 0x80000000u) ? ~u : (u | 0x80000000u);
}
__device__ __forceinline__ float ord2f(unsigned m) {
    return (m & 0x80000000u) ? __uint_as_float(m & 0x7FFFFFFFu) : __uint_as_float(~m);
}

// Ticket grid-barrier. INVARIANT (r15 post-mortem): bar MUST start at a
// multiple of FB each launch — guaranteed by the hipMemsetAsync in
// kernel_launch (harness poisons d_ws to 0xAA; a poisoned bar mid-splits
// an arrival group across two ticket targets -> deadlock, r15's hang).
// Relaxed spin polls + single agent-acquire at exit (r13/r14-validated).
__device__ __forceinline__ void grid_bar(unsigned* bar, int t) {
    __syncthreads();
    if (t == 0) {
        __threadfence();
        const unsigned old = __hip_atomic_fetch_add(bar, 1u, __ATOMIC_ACQ_REL,
                                                    __HIP_MEMORY_SCOPE_AGENT);
        const unsigned target = (old / FB + 1u) * FB;
        while (__hip_atomic_load(bar, __ATOMIC_RELAXED,
                                 __HIP_MEMORY_SCOPE_AGENT) < target)
            __builtin_amdgcn_s_sleep(8);
        __builtin_amdgcn_fence(__ATOMIC_ACQUIRE, "agent");
    }
    __syncthreads();
}

// ---- fused gram + max (no stores in flight across the barrier -> no
// store-drain penalty; the 164MB write stays a separate full-TLP dispatch).
__global__ __launch_bounds__(256, 4) void gram_max(const float* __restrict__ x,
                                                   float* __restrict__ G,
                                                   unsigned* __restrict__ mm,
                                                   unsigned* __restrict__ bar) {
    const int t = threadIdx.x;
    const int w = t >> 6, l = t & 63;
    __shared__ float rg[MI * 8];
    __shared__ float smax[4];

    // ---- phase 1: gram — wave per patch, grid-stride ----
    for (int n = blockIdx.x * 4 + w; n < NP; n += FB * 4) {
        const int pi = n / NPS, pj = n % NPS;
        const int r = l >> 2, c = (l & 3) * 4;
        const size_t base = (size_t)(pi * PS + r) * HW + pj * PS + c;
        const float4 A = *(const float4*)(x + base);
        const float4 B = *(const float4*)(x + base + (size_t)HW * HW);
        const float4 C = *(const float4*)(x + base + 2 * (size_t)HW * HW);
        float p[6];
        p[0] = A.x * A.x + A.y * A.y + A.z * A.z + A.w * A.w;
        p[1] = A.x * B.x + A.y * B.y + A.z * B.z + A.w * B.w;
        p[2] = A.x * C.x + A.y * C.y + A.z * C.z + A.w * C.w;
        p[3] = B.x * B.x + B.y * B.y + B.z * B.z + B.w * B.w;
        p[4] = B.x * C.x + B.y * C.y + B.z * C.z + B.w * C.w;
        p[5] = C.x * C.x + C.y * C.y + C.z * C.z + C.w * C.w;
#pragma unroll
        for (int k = 0; k < 6; ++k) {
            float v = p[k];
#pragma unroll
            for (int off = 32; off; off >>= 1) v += __shfl_xor(v, off);
            p[k] = v;
        }
        if (l == 0) {
            const float sc = 1.0f / 768.0f;
            const float g0 = p[0] * sc, g1 = p[1] * sc, g2 = p[2] * sc;
            const float g3 = p[3] * sc, g4 = p[4] * sc, g5 = p[5] * sc;
            const float row[9] = {g0, g1, g2, g1, g3, g4, g2, g4, g5};
            float s = 0.f;
#pragma unroll
            for (int k = 0; k < 9; ++k) s = fmaf(row[k], row[k], s);
            float* dst = G + (size_t)n * GS;
            *(float4*)(dst)     = make_float4(row[0], row[1], row[2], row[3]);
            *(float4*)(dst + 4) = make_float4(row[4], row[5], row[6], row[7]);
            *(float4*)(dst + 8) = make_float4(row[8], s, 0.f, 0.f);
        }
    }

    grid_bar(bar, t);   // G visible device-wide

    // ---- phase 2: max over upper-band tiles (6-dot form) ----
    float vmax = -3.4e38f;
    for (int tau = blockIdx.x; tau < NT2; tau += FB) {
        const int bi = tau / (NP / MJ), bj = tau % (NP / MJ);
        const int i0 = bi * MI, j0 = bj * MJ;
        if (i0 > j0 + MJ - 1) continue;   // tile entirely below diagonal
        __syncthreads();
        if (t < MI) {
            const float* src = G + (size_t)(i0 + t) * GS;
            const float4 a = *(const float4*)(src);
            const float4 b = *(const float4*)(src + 4);
            const float4 q = *(const float4*)(src + 8);
            float* d = rg + t * 8;
            d[0] = -2.f * a.x; d[1] = -4.f * a.y; d[2] = -4.f * a.z;
            d[3] = -2.f * b.x; d[4] = -4.f * b.y; d[5] = -2.f * q.x;
            d[6] = q.y; d[7] = 0.f;
        }
        __syncthreads();
        const int j = j0 + l * 4;
        float gj[4][6], sj[4];
#pragma unroll
        for (int c = 0; c < 4; ++c) {
            const float* src = G + (size_t)(j + c) * GS;
            const float4 a = *(const float4*)(src);
            const float4 b = *(const float4*)(src + 4);
            const float4 q = *(const float4*)(src + 8);
            gj[c][0] = a.x; gj[c][1] = a.y; gj[c][2] = a.z;
            gj[c][3] = b.x; gj[c][4] = b.y; gj[c][5] = q.x;
            sj[c] = q.y;
        }
#pragma unroll 4
        for (int rr = 0; rr < MI / 4; ++rr) {
            const int r = w * (MI / 4) + rr;
            const float4 A = *(const float4*)(rg + r * 8);
            const float4 B = *(const float4*)(rg + r * 8 + 4);
            const float si = B.z;
#pragma unroll
            for (int c = 0; c < 4; ++c) {
                float acc = si + sj[c];
                acc = fmaf(A.x, gj[c][0], acc);
                acc = fmaf(A.y, gj[c][1], acc);
                acc = fmaf(A.z, gj[c][2], acc);
                acc = fmaf(A.w, gj[c][3], acc);
                acc = fmaf(B.x, gj[c][4], acc);
                acc = fmaf(B.y, gj[c][5], acc);
                vmax = fmaxf(vmax, acc);
            }
        }
    }
#pragma unroll
    for (int off = 32; off; off >>= 1) vmax = fmaxf(vmax, __shfl_xor(vmax, off));
    if (l == 0) smax[w] = vmax;
    __syncthreads();
    if (t == 0) {
        const float bm = fmaxf(fmaxf(smax[0], smax[1]), fmaxf(smax[2], smax[3]));
        atomicMax(mm, f2ord(bm));
    }
    // kernel end = device-wide visibility of mm for the write dispatch
}

// ---- normalized write (r12 geometry; measured ~30us at 5.5 TB/s) ----
__global__ __launch_bounds__(320) void write_kernel(const float* __restrict__ G,
                                                    const unsigned* __restrict__ mm,
                                                    float* __restrict__ out) {
    const int t = threadIdx.x;
    const int w = t >> 6, l = t & 63;
    const int i0 = blockIdx.y * WI;
    const int jw = blockIdx.x * 1280 + w * 256 + l * 4;
    const float inv = 1.f / ord2f(mm[0]);
    __shared__ float rg[WI * 8];
    if (t < WI) {
        const float* src = G + (size_t)(i0 + t) * GS;
        const float4 a = *(const float4*)(src);
        const float4 b = *(const float4*)(src + 4);
        const float4 q = *(const float4*)(src + 8);
        const float m2 = -2.f * inv, m4 = -4.f * inv;
        float* d = rg + t * 8;
        d[0] = m2 * a.x; d[1] = m4 * a.y; d[2] = m4 * a.z;
        d[3] = m2 * b.x; d[4] = m4 * b.y; d[5] = m2 * q.x;
        d[6] = inv * q.y; d[7] = 0.f;
    }
    float gj[4][6], bj[4];
#pragma unroll
    for (int c = 0; c < 4; ++c) {
        const float* src = G + (size_t)(jw + c) * GS;
        const float4 a = *(const float4*)(src);
        const float4 b = *(const float4*)(src + 4);
        const float4 q = *(const float4*)(src + 8);
        gj[c][0] = a.x; gj[c][1] = a.y; gj[c][2] = a.z;
        gj[c][3] = b.x; gj[c][4] = b.y; gj[c][5] = q.x;
        bj[c] = inv * q.y;
    }
    __syncthreads();
    float* dst = out + (size_t)i0 * NP + jw;
#pragma unroll 4
    for (int rr = 0; rr < WI; ++rr) {
        const float4 A = *(const float4*)(rg + rr * 8);
        const float4 B = *(const float4*)(rg + rr * 8 + 4);
        const float hi = B.z;
        vf4 dv;
#pragma unroll
        for (int c = 0; c < 4; ++c) {
            float acc = hi + bj[c];
            acc = fmaf(A.x, gj[c][0], acc);
            acc = fmaf(A.y, gj[c][1], acc);
            acc = fmaf(A.z, gj[c][2], acc);
            acc = fmaf(A.w, gj[c][3], acc);
            acc = fmaf(B.x, gj[c][4], acc);
            acc = fmaf(B.y, gj[c][5], acc);
            dv[c] = acc;
        }
        *(vf4*)dst = dv;
        dst += NP;
    }
}

extern "C" void kernel_launch(void* const* d_in, const int* in_sizes, int n_in,
                              void* d_out, int out_size, void* d_ws, size_t ws_size,
                              hipStream_t stream) {
    (void)in_sizes; (void)n_in; (void)out_size; (void)ws_size;
    const float* x = (const float*)d_in[0];
    float* out = (float*)d_out;
    char* ws = (char*)d_ws;
    float* G = (float*)ws;                       // 307200 B
    unsigned* mm = (unsigned*)(ws + 307200);
    unsigned* bar = mm + 1;

    // REQUIRED: zero mm (max identity) and bar (ticket-barrier invariant:
    // must start at a multiple of FB — d_ws is 0xAA-poisoned by the harness).
    hipMemsetAsync(mm, 0, 8, stream);
    gram_max<<<FB, 256, 0, stream>>>(x, G, mm, bar);
    write_kernel<<<dim3(5, NP / WI), 320, 0, stream>>>(G, mm, out);
}